// Round 5
// baseline (1629.934 us; speedup 1.0000x reference)
//
#include <hip/hip_runtime.h>
#include <math.h>

// Problem constants (b=4, h=8, t=8192, d_h=64, BUCKET=128)
constexpr int NB_B  = 4;
constexpr int NH    = 8;
constexpr int HH    = 4;       // h/2 : heads >= HH are "rotated"
constexpr int NT    = 8192;    // sequence length
constexpr int DH    = 64;      // head dim
constexpr int BSZ   = 128;     // bucket size
constexpr int NBK   = NT / BSZ; // 64 buckets
constexpr int BH    = NB_B * NH; // 32

// -------------------------------------------------------------------------
// Kernel 1a: per (bh, bucket) statistics of the ROTATED q,k:
//   Bq[j,d]  = sum of q over bucket j
//   Bk[j,d]  = sum of k over bucket j
//   q0[j,d]  = q at first position of bucket j
//   skp[j,d] = sum_m k[j*128+m,d] * W[j,m],  W[j,m] = sum_{l>=m} 1/(j*128+l+1)
// -------------------------------------------------------------------------
__global__ __launch_bounds__(256) void k_stats(
    const float* __restrict__ q, const float* __restrict__ k,
    float* __restrict__ Bq, float* __restrict__ Bk,
    float* __restrict__ q0, float* __restrict__ skp)
{
  __shared__ float W[BSZ];
  __shared__ float red[3][4][DH];

  const int bid = blockIdx.x;
  const int bh  = bid >> 6;
  const int j   = bid & 63;
  const int h   = bh & (NH - 1);
  const bool rot = (h >= HH);
  const int t = threadIdx.x;
  const int d = t & 63;
  const int g = t >> 6;          // 4 position groups

  if (t == 0) {
    // suffix sums of reciprocals, double accumulate
    double s = 0.0;
    for (int l = BSZ - 1; l >= 0; --l) {
      s += 1.0 / (double)(j * BSZ + l + 1);
      W[l] = (float)s;
    }
  }
  __syncthreads();

  const float* qb = q + (size_t)bh * NT * DH;
  const float* kb = k + (size_t)bh * NT * DH;

  float sq = 0.f, sk = 0.f, sw = 0.f, q0v = 0.f;
  for (int s5 = 0; s5 < 32; ++s5) {
    const int m = g + 4 * s5;                  // position within bucket
    const int p = j * BSZ + m;
    const int gp = rot ? ((p + BSZ - 1) & (NT - 1)) : p;
    const float qv = qb[(size_t)gp * DH + d];
    const float kv = kb[(size_t)gp * DH + d];
    sq += qv;
    sk += kv;
    sw += kv * W[m];
    if (m == 0) q0v = qv;
  }
  red[0][g][d] = sq;
  red[1][g][d] = sk;
  red[2][g][d] = sw;
  __syncthreads();

  if (t < DH) {
    float a = 0.f, b2 = 0.f, c = 0.f;
    for (int gg = 0; gg < 4; ++gg) {
      a  += red[0][gg][t];
      b2 += red[1][gg][t];
      c  += red[2][gg][t];
    }
    const size_t o = ((size_t)bh * NBK + j) * DH + t;
    Bq[o]  = a;
    Bk[o]  = b2;
    skp[o] = c;
  }
  if (g == 0) {
    const size_t o = ((size_t)bh * NBK + j) * DH + d;
    q0[o] = q0v;   // value captured at m==0
  }
}

// -------------------------------------------------------------------------
// Kernel 1b: per bh — build sq (64x64), sk (65x64), compute the masked
// softmax reordering matrix rows and reduce each row to (argmax col, prob).
// src==0 means "null bucket", src==c means bucket c-1.
// 256 threads: 4 threads per row (column strided by 4).
// -------------------------------------------------------------------------
__global__ __launch_bounds__(256) void k_sortnet(
    const float* __restrict__ Bq, const float* __restrict__ Bk,
    const float* __restrict__ q0, const float* __restrict__ skp,
    float* __restrict__ wgt, int* __restrict__ srcb)
{
  __shared__ float sq[NBK][DH + 1];       // padded: bank-conflict-free
  __shared__ float sk[NBK + 1][DH + 1];
  __shared__ double Hs[NBK];

  const int bh = blockIdx.x;
  const int t  = threadIdx.x;

  if (t < NBK) {
    double s = 0.0;
    for (int l = 0; l < BSZ; ++l) s += 1.0 / (double)(t * BSZ + l + 1);
    Hs[t] = s;
  }
  __syncthreads();

  if (t < DH) {
    const int d = t;
    double pq = 0.0, pk = 0.0;
    sk[0][d] = 0.f;
    for (int j = 0; j < NBK; ++j) {
      const size_t o = ((size_t)bh * NBK + j) * DH + d;
      sq[j][d]     = (float)((pq + (double)q0[o]) / (double)(j * BSZ + 1));
      sk[j + 1][d] = (float)(pk * Hs[j] + (double)skp[o]);
      pq += (double)Bq[o];
      pk += (double)Bk[o];
    }
  }
  __syncthreads();

  const int i  = t >> 2;   // row 0..63
  const int qt = t & 3;    // column quarter

  float rq[DH];
#pragma unroll
  for (int d = 0; d < DH; ++d) rq[d] = sq[i][d];

  float Mp = -1e30f, bestp = -1e30f;
  int bcp = 1 << 30;
  float dts[16];
#pragma unroll
  for (int cc = 0; cc < 16; ++cc) {
    const int c = qt + 4 * cc;
    float dt2 = -1e30f;
    if (c <= i) {                       // columns > i are masked (-inf)
      double a2 = 0.0;
      for (int d = 0; d < DH; ++d) a2 += (double)rq[d] * (double)sk[c][d];
      dt2 = (float)(a2 * 0.125);
      Mp = fmaxf(Mp, dt2);
      if (c <= i - 1 && dt2 > bestp) { bestp = dt2; bcp = c; }
    }
    dts[cc] = dt2;
  }
  // combine the 4 column-quarters of this row (lanes qt = 0..3)
  for (int off = 1; off <= 2; off <<= 1) {
    const float oM  = __shfl_xor(Mp, off);
    const float ob  = __shfl_xor(bestp, off);
    const int   obc = __shfl_xor(bcp, off);
    Mp = fmaxf(Mp, oM);
    if (ob > bestp || (ob == bestp && obc < bcp)) { bestp = ob; bcp = obc; }
  }
  float Dp = 0.f;
#pragma unroll
  for (int cc = 0; cc < 16; ++cc) {
    const int c = qt + 4 * cc;
    if (c <= i) Dp += __expf(dts[cc] - Mp);
  }
  Dp += __shfl_xor(Dp, 1);
  Dp += __shfl_xor(Dp, 2);

  if (qt == 0) {
    const bool has = (i >= 1);
    wgt[bh * NBK + i]  = has ? (__expf(bestp - Mp) / Dp) : 0.f;
    srcb[bh * NBK + i] = has ? bcp : 0;
  }
}

// -------------------------------------------------------------------------
// Kernel 2: bucketed attention. One block per (bh, bucket u), 128 threads,
// one q-row per thread (q + accumulator in registers). K/V rows are read
// with wave-uniform addresses (scalarizable loads). Key list:
//   j in [0,128)  : w * K[src]  (or w * null row)   -- logits scaled by w
//   j in [128,256): own bucket, causal
// Online softmax with chunk-of-8 deferred rescale; causal chunk skip.
// -------------------------------------------------------------------------
__global__ __launch_bounds__(128) void k_attn(
    const float* __restrict__ q, const float* __restrict__ k,
    const float* __restrict__ v,
    const float* __restrict__ nullk, const float* __restrict__ nullv,
    const float* __restrict__ wgt, const int* __restrict__ srcb,
    float* __restrict__ out)
{
  const int bid = blockIdx.x;
  const int bh  = bid >> 6;
  const int u   = bid & 63;
  const int h   = bh & (NH - 1);
  const bool rot     = (h >= HH);
  const bool special = rot && (u == NBK - 1);
  const int r = threadIdx.x;                 // q row within bucket

  const float* qb = q + (size_t)bh * NT * DH;
  const float* kb = k + (size_t)bh * NT * DH;
  const float* vb = v + (size_t)bh * NT * DH;

  const int pos  = u * BSZ + r;
  const int gpos = rot ? ((pos + BSZ - 1) & (NT - 1)) : pos;

  float4 qr[16];
  {
    const float4* qp = (const float4*)(qb + (size_t)gpos * DH);
#pragma unroll
    for (int i = 0; i < 16; ++i) qr[i] = qp[i];
  }

  const float w = wgt[bh * NBK + u];
  const int   s = srcb[bh * NBK + u];

  float acc[DH];
#pragma unroll
  for (int i = 0; i < DH; ++i) acc[i] = 0.f;
  float m = -1e30f, l = 0.f;

  // ---------------- first half: reordered keys ----------------
  const bool valid1 = (!special) || (r == 0);
  if (valid1) {
    const float cw1 = 0.125f * w;
    const float* kb1 = (s == 0) ? (nullk + h * DH) : kb;
    const float* vb1 = (s == 0) ? (nullv + h * DH) : vb;
    const int base1  = (s == 0) ? 0 : (s - 1) * BSZ;

    for (int ch = 0; ch < BSZ / 8; ++ch) {
      float dv[8];
#pragma unroll
      for (int kk = 0; kk < 8; ++kk) {
        const int jj = ch * 8 + kk;
        size_t off = 0;
        if (s != 0) {
          const int p  = base1 + jj;
          const int gp = rot ? ((p + BSZ - 1) & (NT - 1)) : p;
          off = (size_t)gp * DH;
        }
        const float4* kp = (const float4*)(kb1 + off);
        float dt2 = 0.f;
#pragma unroll
        for (int i = 0; i < 16; ++i) {
          const float4 kv = kp[i];
          dt2 += qr[i].x * kv.x + qr[i].y * kv.y + qr[i].z * kv.z + qr[i].w * kv.w;
        }
        dv[kk] = dt2 * cw1;
      }
      float cmax = dv[0];
#pragma unroll
      for (int kk = 1; kk < 8; ++kk) cmax = fmaxf(cmax, dv[kk]);
      const float mn   = fmaxf(m, cmax);
      const float corr = __expf(m - mn);
      l *= corr;
#pragma unroll
      for (int i = 0; i < DH; ++i) acc[i] *= corr;
      m = mn;
#pragma unroll
      for (int kk = 0; kk < 8; ++kk) {
        const int jj = ch * 8 + kk;
        const float p2 = __expf(dv[kk] - m);
        l += p2;
        const float coef = p2 * w;               // fold reorder weight into PV
        size_t off = 0;
        if (s != 0) {
          const int p  = base1 + jj;
          const int gp = rot ? ((p + BSZ - 1) & (NT - 1)) : p;
          off = (size_t)gp * DH;
        }
        const float4* vp = (const float4*)(vb1 + off);
#pragma unroll
        for (int i = 0; i < 16; ++i) {
          const float4 v4 = vp[i];
          acc[4 * i + 0] += coef * v4.x;
          acc[4 * i + 1] += coef * v4.y;
          acc[4 * i + 2] += coef * v4.z;
          acc[4 * i + 3] += coef * v4.w;
        }
      }
    }
  }

  // ---------------- second half: own bucket (causal) ----------------
  const int lo2 = (special && r > 0) ? 1 : 0;
  const int hi2 = (special && r == 0) ? 0 : r;
  const int nch = (hi2 >> 3) + 1;     // causal skip: chunks past row are all-masked
  for (int ch = 0; ch < nch; ++ch) {
    float dv[8];
#pragma unroll
    for (int kk = 0; kk < 8; ++kk) {
      const int jj = ch * 8 + kk;
      const int p  = u * BSZ + jj;
      const int gp = rot ? ((p + BSZ - 1) & (NT - 1)) : p;
      const float4* kp = (const float4*)(kb + (size_t)gp * DH);
      float dt2 = 0.f;
#pragma unroll
      for (int i = 0; i < 16; ++i) {
        const float4 kv = kp[i];
        dt2 += qr[i].x * kv.x + qr[i].y * kv.y + qr[i].z * kv.z + qr[i].w * kv.w;
      }
      const bool vld = (jj >= lo2) && (jj <= hi2);
      dv[kk] = vld ? dt2 * 0.125f : -1e30f;
    }
    float cmax = dv[0];
#pragma unroll
    for (int kk = 1; kk < 8; ++kk) cmax = fmaxf(cmax, dv[kk]);
    const float mn   = fmaxf(m, cmax);
    const float corr = __expf(m - mn);
    l *= corr;
#pragma unroll
    for (int i = 0; i < DH; ++i) acc[i] *= corr;
    m = mn;
#pragma unroll
    for (int kk = 0; kk < 8; ++kk) {
      const int jj = ch * 8 + kk;
      const float p2 = __expf(dv[kk] - m);   // exp(-1e30 - m) == 0 for masked
      l += p2;
      const int p  = u * BSZ + jj;
      const int gp = rot ? ((p + BSZ - 1) & (NT - 1)) : p;
      const float4* vp = (const float4*)(vb + (size_t)gp * DH);
#pragma unroll
      for (int i = 0; i < 16; ++i) {
        const float4 v4 = vp[i];
        acc[4 * i + 0] += p2 * v4.x;
        acc[4 * i + 1] += p2 * v4.y;
        acc[4 * i + 2] += p2 * v4.z;
        acc[4 * i + 3] += p2 * v4.w;
      }
    }
  }

  const float rl = 1.0f / l;
  // output inverse-rotation is the same index map as the input rotation
  float4* op = (float4*)(out + ((size_t)bh * NT + gpos) * DH);
#pragma unroll
  for (int i = 0; i < 16; ++i)
    op[i] = make_float4(acc[4 * i] * rl, acc[4 * i + 1] * rl,
                        acc[4 * i + 2] * rl, acc[4 * i + 3] * rl);
}

// -------------------------------------------------------------------------
extern "C" void kernel_launch(void* const* d_in, const int* in_sizes, int n_in,
                              void* d_out, int out_size, void* d_ws, size_t ws_size,
                              hipStream_t stream) {
  const float* q  = (const float*)d_in[0];
  const float* k  = (const float*)d_in[1];
  const float* v  = (const float*)d_in[2];
  const float* nk = (const float*)d_in[3];
  const float* nv = (const float*)d_in[4];
  float* out = (float*)d_out;

  float* wsf  = (float*)d_ws;
  float* wgt  = wsf;                              // BH*NBK floats
  int*   srcb = (int*)(wsf + BH * NBK);           // BH*NBK ints
  float* Bq   = wsf + 2 * BH * NBK;
  float* Bk   = Bq + (size_t)BH * NBK * DH;
  float* q0   = Bk + (size_t)BH * NBK * DH;
  float* skp  = q0 + (size_t)BH * NBK * DH;
  // total: 2*2048 + 4*131072 floats ~= 2.1 MB of workspace

  hipLaunchKernelGGL(k_stats, dim3(BH * NBK), dim3(256), 0, stream,
                     q, k, Bq, Bk, q0, skp);
  hipLaunchKernelGGL(k_sortnet, dim3(BH), dim3(256), 0, stream,
                     Bq, Bk, q0, skp, wgt, srcb);
  hipLaunchKernelGGL(k_attn, dim3(BH * NBK), dim3(128), 0, stream,
                     q, k, v, nk, nv, wgt, srcb, out);
}

// Round 6
// 635.826 us; speedup vs baseline: 2.5635x; 2.5635x over previous
//
#include <hip/hip_runtime.h>
#include <math.h>

// Problem constants (b=4, h=8, t=8192, d_h=64, BUCKET=128)
constexpr int NB_B  = 4;
constexpr int NH    = 8;
constexpr int HH    = 4;       // h/2 : heads >= HH are "rotated"
constexpr int NT    = 8192;    // sequence length
constexpr int DH    = 64;      // head dim
constexpr int BSZ   = 128;     // bucket size
constexpr int NBK   = NT / BSZ; // 64 buckets
constexpr int BH    = NB_B * NH; // 32

// -------------------------------------------------------------------------
// Kernel 1a: per (bh, bucket) statistics of the ROTATED q,k  (unchanged)
// -------------------------------------------------------------------------
__global__ __launch_bounds__(256) void k_stats(
    const float* __restrict__ q, const float* __restrict__ k,
    float* __restrict__ Bq, float* __restrict__ Bk,
    float* __restrict__ q0, float* __restrict__ skp)
{
  __shared__ float W[BSZ];
  __shared__ float red[3][4][DH];

  const int bid = blockIdx.x;
  const int bh  = bid >> 6;
  const int j   = bid & 63;
  const int h   = bh & (NH - 1);
  const bool rot = (h >= HH);
  const int t = threadIdx.x;
  const int d = t & 63;
  const int g = t >> 6;          // 4 position groups

  if (t == 0) {
    double s = 0.0;
    for (int l = BSZ - 1; l >= 0; --l) {
      s += 1.0 / (double)(j * BSZ + l + 1);
      W[l] = (float)s;
    }
  }
  __syncthreads();

  const float* qb = q + (size_t)bh * NT * DH;
  const float* kb = k + (size_t)bh * NT * DH;

  float sq = 0.f, sk = 0.f, sw = 0.f, q0v = 0.f;
  for (int s5 = 0; s5 < 32; ++s5) {
    const int m = g + 4 * s5;                  // position within bucket
    const int p = j * BSZ + m;
    const int gp = rot ? ((p + BSZ - 1) & (NT - 1)) : p;
    const float qv = qb[(size_t)gp * DH + d];
    const float kv = kb[(size_t)gp * DH + d];
    sq += qv;
    sk += kv;
    sw += kv * W[m];
    if (m == 0) q0v = qv;
  }
  red[0][g][d] = sq;
  red[1][g][d] = sk;
  red[2][g][d] = sw;
  __syncthreads();

  if (t < DH) {
    float a = 0.f, b2 = 0.f, c = 0.f;
    for (int gg = 0; gg < 4; ++gg) {
      a  += red[0][gg][t];
      b2 += red[1][gg][t];
      c  += red[2][gg][t];
    }
    const size_t o = ((size_t)bh * NBK + j) * DH + t;
    Bq[o]  = a;
    Bk[o]  = b2;
    skp[o] = c;
  }
  if (g == 0) {
    const size_t o = ((size_t)bh * NBK + j) * DH + d;
    q0[o] = q0v;
  }
}

// -------------------------------------------------------------------------
// Kernel 1b: sort_net reduction to (src bucket, weight)  (unchanged)
// -------------------------------------------------------------------------
__global__ __launch_bounds__(256) void k_sortnet(
    const float* __restrict__ Bq, const float* __restrict__ Bk,
    const float* __restrict__ q0, const float* __restrict__ skp,
    float* __restrict__ wgt, int* __restrict__ srcb)
{
  __shared__ float sq[NBK][DH + 1];
  __shared__ float sk[NBK + 1][DH + 1];
  __shared__ double Hs[NBK];

  const int bh = blockIdx.x;
  const int t  = threadIdx.x;

  if (t < NBK) {
    double s = 0.0;
    for (int l = 0; l < BSZ; ++l) s += 1.0 / (double)(t * BSZ + l + 1);
    Hs[t] = s;
  }
  __syncthreads();

  if (t < DH) {
    const int d = t;
    double pq = 0.0, pk = 0.0;
    sk[0][d] = 0.f;
    for (int j = 0; j < NBK; ++j) {
      const size_t o = ((size_t)bh * NBK + j) * DH + d;
      sq[j][d]     = (float)((pq + (double)q0[o]) / (double)(j * BSZ + 1));
      sk[j + 1][d] = (float)(pk * Hs[j] + (double)skp[o]);
      pq += (double)Bq[o];
      pk += (double)Bk[o];
    }
  }
  __syncthreads();

  const int i  = t >> 2;   // row 0..63
  const int qt = t & 3;    // column quarter

  float rq[DH];
#pragma unroll
  for (int d = 0; d < DH; ++d) rq[d] = sq[i][d];

  float Mp = -1e30f, bestp = -1e30f;
  int bcp = 1 << 30;
  float dts[16];
#pragma unroll
  for (int cc = 0; cc < 16; ++cc) {
    const int c = qt + 4 * cc;
    float dt2 = -1e30f;
    if (c <= i) {
      double a2 = 0.0;
      for (int d = 0; d < DH; ++d) a2 += (double)rq[d] * (double)sk[c][d];
      dt2 = (float)(a2 * 0.125);
      Mp = fmaxf(Mp, dt2);
      if (c <= i - 1 && dt2 > bestp) { bestp = dt2; bcp = c; }
    }
    dts[cc] = dt2;
  }
  for (int off = 1; off <= 2; off <<= 1) {
    const float oM  = __shfl_xor(Mp, off);
    const float ob  = __shfl_xor(bestp, off);
    const int   obc = __shfl_xor(bcp, off);
    Mp = fmaxf(Mp, oM);
    if (ob > bestp || (ob == bestp && obc < bcp)) { bestp = ob; bcp = obc; }
  }
  float Dp = 0.f;
#pragma unroll
  for (int cc = 0; cc < 16; ++cc) {
    const int c = qt + 4 * cc;
    if (c <= i) Dp += __expf(dts[cc] - Mp);
  }
  Dp += __shfl_xor(Dp, 1);
  Dp += __shfl_xor(Dp, 2);

  if (qt == 0) {
    const bool has = (i >= 1);
    wgt[bh * NBK + i]  = has ? (__expf(bestp - Mp) / Dp) : 0.f;
    srcb[bh * NBK + i] = has ? bcp : 0;
  }
}

// -------------------------------------------------------------------------
// Kernel 2 (REWRITTEN): LDS-staged, double-buffered bucketed attention.
// Block = one (bh, u), 256 threads = 128 rows x 2 dim-halves.
//   - thread (r, hf) holds q[32] and acc[32] (dims hf*32..hf*32+31)
//   - full 64-dim dot = partial + __shfl_xor(partial, 32)  (pair in same wave)
//   - K/V chunks of 32 keys staged to LDS cooperatively (coalesced),
//     double-buffered; compute reads are broadcast ds_read_b128
//   - s==0 (null bucket): closed form (128 identical keys), no staging
// -------------------------------------------------------------------------
__global__ __launch_bounds__(256, 2) void k_attn(
    const float* __restrict__ q, const float* __restrict__ k,
    const float* __restrict__ v,
    const float* __restrict__ nullk, const float* __restrict__ nullv,
    const float* __restrict__ wgt, const int* __restrict__ srcb,
    float* __restrict__ out)
{
  __shared__ float sK[2][32][64];   // 16 KB
  __shared__ float sV[2][32][64];   // 16 KB

  const int bid = blockIdx.x;
  const int bh  = bid >> 6;
  const int u   = bid & 63;
  const int h   = bh & (NH - 1);
  const bool rot     = (h >= HH);
  const bool special = rot && (u == NBK - 1);

  const int t    = threadIdx.x;
  const int wv   = t >> 6;            // wave 0..3
  const int lane = t & 63;
  const int r    = wv * 32 + (lane & 31);   // q row 0..127
  const int hf   = lane >> 5;               // dim half
  const int d0   = hf * 32;

  const float* qb = q + (size_t)bh * NT * DH;
  const float* kb = k + (size_t)bh * NT * DH;
  const float* vb = v + (size_t)bh * NT * DH;

  const int pos  = u * BSZ + r;
  const int gpos = rot ? ((pos + BSZ - 1) & (NT - 1)) : pos;

  float4 qr[8];
  {
    const float4* qp = (const float4*)(qb + (size_t)gpos * DH + d0);
#pragma unroll
    for (int i = 0; i < 8; ++i) qr[i] = qp[i];
  }

  const float wq  = wgt[bh * NBK + u];
  const int   s   = srcb[bh * NBK + u];
  const float cw1 = 0.125f * wq;

  const bool valid1 = (!special) || (r == 0);
  const int lo2 = (special && r > 0) ? 1 : 0;
  const int hi2 = (special && r == 0) ? 0 : r;

  float acc[32];
#pragma unroll
  for (int i = 0; i < 32; ++i) acc[i] = 0.f;
  float m = -1e30f, l = 0.f;

  // ---- first half, null-bucket case: 128 identical keys, closed form ----
  if (s == 0) {
    if (valid1) {
      float pn = 0.f;
      const float* np = nullk + h * DH + d0;
#pragma unroll
      for (int i = 0; i < 8; ++i) {
        const float4 n4 = *(const float4*)(np + 4 * i);
        pn += qr[i].x * n4.x + qr[i].y * n4.y + qr[i].z * n4.z + qr[i].w * n4.w;
      }
      const float L0 = (pn + __shfl_xor(pn, 32)) * cw1;
      m = L0;                         // first online-softmax update
      l = 128.f;                      // 128 * exp(L0 - m)
      const float coef = 128.f * wq;  // fold reorder weight into PV
      const float* nv2 = nullv + h * DH + d0;
#pragma unroll
      for (int i = 0; i < 8; ++i) {
        const float4 v4 = *(const float4*)(nv2 + 4 * i);
        acc[4 * i + 0] += coef * v4.x;
        acc[4 * i + 1] += coef * v4.y;
        acc[4 * i + 2] += coef * v4.z;
        acc[4 * i + 3] += coef * v4.w;
      }
    }
  }

  const int aCh     = (s != 0) ? 4 : 0;   // chunks of reordered first half
  const int nCh     = aCh + 4;            // + 4 chunks of own bucket
  const int srcBase = (s - 1) * BSZ;      // only used when s != 0
  const int ownBase = u * BSZ;

  auto stage = [&](int buf, int cc) {
    const int row0 = (cc < aCh) ? (srcBase + cc * 32)
                                : (ownBase + (cc - aCh) * 32);
#pragma unroll
    for (int i = 0; i < 2; ++i) {
      const int f   = t + 256 * i;        // 0..511
      const int row = f >> 4;             // 0..31
      const int col = (f & 15) * 4;       // 0..60
      const int p   = row0 + row;
      const int gp  = rot ? ((p + BSZ - 1) & (NT - 1)) : p;
      *(float4*)&sK[buf][row][col] = *(const float4*)(kb + (size_t)gp * DH + col);
      *(float4*)&sV[buf][row][col] = *(const float4*)(vb + (size_t)gp * DH + col);
    }
  };

  stage(0, 0);
  __syncthreads();
  int cur = 0;

  for (int cc = 0; cc < nCh; ++cc) {
    if (cc + 1 < nCh) stage(cur ^ 1, cc + 1);   // prefetch next chunk

    const bool isA   = (cc < aCh);
    const int  j0    = isA ? cc * 32 : (cc - aCh) * 32;
    const float scale = isA ? cw1 : 0.125f;
    const float pvw   = isA ? wq : 1.f;
    const bool doIt = isA ? valid1 : (j0 <= hi2);

    if (doIt) {
#pragma unroll
      for (int sub = 0; sub < 2; ++sub) {
        if (!isA && (j0 + sub * 16) > hi2) break;  // causal sub-chunk skip
        float dvv[16];
#pragma unroll
        for (int kk = 0; kk < 16; ++kk) {
          const int key = sub * 16 + kk;
          const float* krow = &sK[cur][key][d0];
          float pd = 0.f;
#pragma unroll
          for (int i = 0; i < 8; ++i) {
            const float4 k4 = *(const float4*)(krow + 4 * i);
            pd += qr[i].x * k4.x + qr[i].y * k4.y + qr[i].z * k4.z + qr[i].w * k4.w;
          }
          const float full = pd + __shfl_xor(pd, 32);
          const int j = j0 + key;
          const bool vld = isA || (j >= lo2 && j <= hi2);
          dvv[kk] = vld ? full * scale : -1e30f;
        }
        float cmax = dvv[0];
#pragma unroll
        for (int kk = 1; kk < 16; ++kk) cmax = fmaxf(cmax, dvv[kk]);
        const float mn   = fmaxf(m, cmax);
        const float corr = __expf(m - mn);
        l *= corr;
#pragma unroll
        for (int i = 0; i < 32; ++i) acc[i] *= corr;
        m = mn;
#pragma unroll
        for (int kk = 0; kk < 16; ++kk) {
          const float p2 = __expf(dvv[kk] - m);
          l += p2;
          const float coef = p2 * pvw;
          const float* vrow = &sV[cur][sub * 16 + kk][d0];
#pragma unroll
          for (int i = 0; i < 8; ++i) {
            const float4 v4 = *(const float4*)(vrow + 4 * i);
            acc[4 * i + 0] += coef * v4.x;
            acc[4 * i + 1] += coef * v4.y;
            acc[4 * i + 2] += coef * v4.z;
            acc[4 * i + 3] += coef * v4.w;
          }
        }
      }
    }
    __syncthreads();
    cur ^= 1;
  }

  const float rl = 1.0f / l;
  float4* op = (float4*)(out + ((size_t)bh * NT + gpos) * DH + d0);
#pragma unroll
  for (int i = 0; i < 8; ++i)
    op[i] = make_float4(acc[4 * i] * rl, acc[4 * i + 1] * rl,
                        acc[4 * i + 2] * rl, acc[4 * i + 3] * rl);
}

// -------------------------------------------------------------------------
extern "C" void kernel_launch(void* const* d_in, const int* in_sizes, int n_in,
                              void* d_out, int out_size, void* d_ws, size_t ws_size,
                              hipStream_t stream) {
  const float* q  = (const float*)d_in[0];
  const float* k  = (const float*)d_in[1];
  const float* v  = (const float*)d_in[2];
  const float* nk = (const float*)d_in[3];
  const float* nv = (const float*)d_in[4];
  float* out = (float*)d_out;

  float* wsf  = (float*)d_ws;
  float* wgt  = wsf;                              // BH*NBK floats
  int*   srcb = (int*)(wsf + BH * NBK);           // BH*NBK ints
  float* Bq   = wsf + 2 * BH * NBK;
  float* Bk   = Bq + (size_t)BH * NBK * DH;
  float* q0   = Bk + (size_t)BH * NBK * DH;
  float* skp  = q0 + (size_t)BH * NBK * DH;

  hipLaunchKernelGGL(k_stats, dim3(BH * NBK), dim3(256), 0, stream,
                     q, k, Bq, Bk, q0, skp);
  hipLaunchKernelGGL(k_sortnet, dim3(BH), dim3(256), 0, stream,
                     Bq, Bk, q0, skp, wgt, srcb);
  hipLaunchKernelGGL(k_attn, dim3(BH * NBK), dim3(256), 0, stream,
                     q, k, v, nk, nv, wgt, srcb, out);
}

// Round 7
// 421.307 us; speedup vs baseline: 3.8688x; 1.5092x over previous
//
#include <hip/hip_runtime.h>
#include <math.h>

// Problem constants (b=4, h=8, t=8192, d_h=64, BUCKET=128)
constexpr int NB_B  = 4;
constexpr int NH    = 8;
constexpr int HH    = 4;       // h/2 : heads >= HH are "rotated"
constexpr int NT    = 8192;    // sequence length
constexpr int DH    = 64;      // head dim
constexpr int BSZ   = 128;     // bucket size
constexpr int NBK   = NT / BSZ; // 64 buckets
constexpr int BH    = NB_B * NH; // 32

typedef __attribute__((ext_vector_type(8))) short   bfrag;   // 8 bf16 = 4 VGPR (MFMA A/B)
typedef __attribute__((ext_vector_type(4))) float   ffrag;   // 4 f32 (MFMA C/D)
typedef __attribute__((ext_vector_type(4))) unsigned short u16x4;

__device__ inline unsigned short bfhi(float f) {
  union { float f; unsigned u; } x; x.f = f;
  return (unsigned short)(x.u >> 16);          // truncation; remainder goes to lo
}
__device__ inline float bf2f(unsigned short s) {
  union { unsigned u; float f; } x; x.u = ((unsigned)s) << 16;
  return x.f;
}

// -------------------------------------------------------------------------
// Kernel 1a: per (bh, bucket) statistics of the ROTATED q,k  (unchanged)
// -------------------------------------------------------------------------
__global__ __launch_bounds__(256) void k_stats(
    const float* __restrict__ q, const float* __restrict__ k,
    float* __restrict__ Bq, float* __restrict__ Bk,
    float* __restrict__ q0, float* __restrict__ skp)
{
  __shared__ float W[BSZ];
  __shared__ float red[3][4][DH];

  const int bid = blockIdx.x;
  const int bh  = bid >> 6;
  const int j   = bid & 63;
  const int h   = bh & (NH - 1);
  const bool rot = (h >= HH);
  const int t = threadIdx.x;
  const int d = t & 63;
  const int g = t >> 6;

  if (t == 0) {
    double s = 0.0;
    for (int l = BSZ - 1; l >= 0; --l) {
      s += 1.0 / (double)(j * BSZ + l + 1);
      W[l] = (float)s;
    }
  }
  __syncthreads();

  const float* qb = q + (size_t)bh * NT * DH;
  const float* kb = k + (size_t)bh * NT * DH;

  float sq = 0.f, sk = 0.f, sw = 0.f, q0v = 0.f;
  for (int s5 = 0; s5 < 32; ++s5) {
    const int m = g + 4 * s5;
    const int p = j * BSZ + m;
    const int gp = rot ? ((p + BSZ - 1) & (NT - 1)) : p;
    const float qv = qb[(size_t)gp * DH + d];
    const float kv = kb[(size_t)gp * DH + d];
    sq += qv; sk += kv; sw += kv * W[m];
    if (m == 0) q0v = qv;
  }
  red[0][g][d] = sq;
  red[1][g][d] = sk;
  red[2][g][d] = sw;
  __syncthreads();

  if (t < DH) {
    float a = 0.f, b2 = 0.f, c = 0.f;
    for (int gg = 0; gg < 4; ++gg) {
      a += red[0][gg][t]; b2 += red[1][gg][t]; c += red[2][gg][t];
    }
    const size_t o = ((size_t)bh * NBK + j) * DH + t;
    Bq[o] = a; Bk[o] = b2; skp[o] = c;
  }
  if (g == 0) {
    const size_t o = ((size_t)bh * NBK + j) * DH + d;
    q0[o] = q0v;
  }
}

// -------------------------------------------------------------------------
// Kernel 1b: sort_net reduction to (src bucket, weight)  (unchanged)
// -------------------------------------------------------------------------
__global__ __launch_bounds__(256) void k_sortnet(
    const float* __restrict__ Bq, const float* __restrict__ Bk,
    const float* __restrict__ q0, const float* __restrict__ skp,
    float* __restrict__ wgt, int* __restrict__ srcb)
{
  __shared__ float sq[NBK][DH + 1];
  __shared__ float sk[NBK + 1][DH + 1];
  __shared__ double Hs[NBK];

  const int bh = blockIdx.x;
  const int t  = threadIdx.x;

  if (t < NBK) {
    double s = 0.0;
    for (int l = 0; l < BSZ; ++l) s += 1.0 / (double)(t * BSZ + l + 1);
    Hs[t] = s;
  }
  __syncthreads();

  if (t < DH) {
    const int d = t;
    double pq = 0.0, pk = 0.0;
    sk[0][d] = 0.f;
    for (int j = 0; j < NBK; ++j) {
      const size_t o = ((size_t)bh * NBK + j) * DH + d;
      sq[j][d]     = (float)((pq + (double)q0[o]) / (double)(j * BSZ + 1));
      sk[j + 1][d] = (float)(pk * Hs[j] + (double)skp[o]);
      pq += (double)Bq[o];
      pk += (double)Bk[o];
    }
  }
  __syncthreads();

  const int i  = t >> 2;
  const int qt = t & 3;

  float rq[DH];
#pragma unroll
  for (int d = 0; d < DH; ++d) rq[d] = sq[i][d];

  float Mp = -1e30f, bestp = -1e30f;
  int bcp = 1 << 30;
  float dts[16];
#pragma unroll
  for (int cc = 0; cc < 16; ++cc) {
    const int c = qt + 4 * cc;
    float dt2 = -1e30f;
    if (c <= i) {
      double a2 = 0.0;
      for (int d = 0; d < DH; ++d) a2 += (double)rq[d] * (double)sk[c][d];
      dt2 = (float)(a2 * 0.125);
      Mp = fmaxf(Mp, dt2);
      if (c <= i - 1 && dt2 > bestp) { bestp = dt2; bcp = c; }
    }
    dts[cc] = dt2;
  }
  for (int off = 1; off <= 2; off <<= 1) {
    const float oM  = __shfl_xor(Mp, off);
    const float ob  = __shfl_xor(bestp, off);
    const int   obc = __shfl_xor(bcp, off);
    Mp = fmaxf(Mp, oM);
    if (ob > bestp || (ob == bestp && obc < bcp)) { bestp = ob; bcp = obc; }
  }
  float Dp = 0.f;
#pragma unroll
  for (int cc = 0; cc < 16; ++cc) {
    const int c = qt + 4 * cc;
    if (c <= i) Dp += __expf(dts[cc] - Mp);
  }
  Dp += __shfl_xor(Dp, 1);
  Dp += __shfl_xor(Dp, 2);

  if (qt == 0) {
    const bool has = (i >= 1);
    wgt[bh * NBK + i]  = has ? (__expf(bestp - Mp) / Dp) : 0.f;
    srcb[bh * NBK + i] = has ? bcp : 0;
  }
}

// -------------------------------------------------------------------------
// Kernel 2 (MFMA rewrite): one block per (bh,u), 4 waves x 64.
// Wave w owns q-rows [w*32, w*32+32) = 2 row-tiles of 16.
// Per 32-key chunk: QK^T and PV on v_mfma_f32_16x16x32_bf16 with split-bf16
// (hi+lo) operands: 3 products per GEMM -> fp32-level accuracy.
//  - sK: pre-split bf16, row-XOR swizzle (^((key&7)<<3) on ushort idx)
//  - sVT: pre-split bf16, TRANSPOSED [dim][key] pad 40 -> B-frag = 1 b128
//  - sP: per-wave P transpose buffer [16][40] (wave-internal sync only)
// Online softmax in C-frag layout; explicit valid-mask on P (all-masked
// tiles must contribute 0, not exp(0)); null bucket staged as 32 copies
// with multiplicity 4 folded into l and P.
// -------------------------------------------------------------------------
__global__ __launch_bounds__(256) void k_attn(
    const float* __restrict__ q, const float* __restrict__ k,
    const float* __restrict__ v,
    const float* __restrict__ nullk, const float* __restrict__ nullv,
    const float* __restrict__ wgt, const int* __restrict__ srcb,
    float* __restrict__ out)
{
  __shared__ __align__(16) unsigned short sK [2][2][32 * 64];  // [buf][h/l][key*64 + (dim^swz)]
  __shared__ __align__(16) unsigned short sVT[2][2][64 * 40];  // [buf][h/l][dim*40 + key]
  __shared__ __align__(16) unsigned short sP [4][2][16 * 40];  // [wave][h/l][row*40 + key]

  const int bid = blockIdx.x;
  const int bh  = bid >> 6;
  const int u   = bid & 63;
  const int h   = bh & (NH - 1);
  const bool rot     = (h >= HH);
  const bool special = rot && (u == NBK - 1);

  const int t  = threadIdx.x;
  const int w  = t >> 6;       // wave 0..3
  const int l  = t & 63;
  const int lg = l >> 4;       // 16-lane group 0..3
  const int lc = l & 15;       // col / row-in-16

  const float* qb = q + (size_t)bh * NT * DH;
  const float* kb = k + (size_t)bh * NT * DH;
  const float* vb = v + (size_t)bh * NT * DH;

  const float wq  = wgt[bh * NBK + u];
  const int   s   = srcb[bh * NBK + u];
  const float cw1 = 0.125f * wq;
  const int aCh = (s != 0) ? 4 : 1;      // first-half chunks (null: 1 chunk x mult 4)
  const int nCh = aCh + 4;

  // ---- Q A-frags (persistent): row = w*32 + rt*16 + lc, k = kh*32 + 8*lg + i
  bfrag qh[2][2], ql[2][2];
#pragma unroll
  for (int rt = 0; rt < 2; ++rt) {
    const int row  = w * 32 + rt * 16 + lc;
    const int pos  = u * BSZ + row;
    const int gpos = rot ? ((pos + BSZ - 1) & (NT - 1)) : pos;
#pragma unroll
    for (int kh = 0; kh < 2; ++kh) {
      const float* qp = qb + (size_t)gpos * DH + kh * 32 + lg * 8;
      const float4 a = *(const float4*)qp;
      const float4 b = *(const float4*)(qp + 4);
      const float vals[8] = {a.x, a.y, a.z, a.w, b.x, b.y, b.z, b.w};
#pragma unroll
      for (int i = 0; i < 8; ++i) {
        const unsigned short hi = bfhi(vals[i]);
        qh[rt][kh][i] = (short)hi;
        ql[rt][kh][i] = (short)bfhi(vals[i] - bf2f(hi));
      }
    }
  }

  ffrag O[2][4];
  float mR[2][4], lR[2][4];
#pragma unroll
  for (int rt = 0; rt < 2; ++rt)
#pragma unroll
    for (int x = 0; x < 4; ++x) {
      O[rt][x] = ffrag{0.f, 0.f, 0.f, 0.f};
      mR[rt][x] = -1e30f; lR[rt][x] = 0.f;
    }

  // ---- staging: regs <- global (early), LDS <- regs (late, after compute)
  float4 rK[2], rV[2];
  auto LD = [&](int cc) {
#pragma unroll
    for (int it = 0; it < 2; ++it) {
      const int f   = t + 256 * it;
      const int key = f >> 4;             // 0..31
      const int c0  = (f & 15) * 4;       // 0..60
      if (cc < aCh && s == 0) {
        rK[it] = *(const float4*)(nullk + h * DH + c0);
        rV[it] = *(const float4*)(nullv + h * DH + c0);
      } else {
        const int base = (cc < aCh) ? ((s - 1) * BSZ + cc * 32)
                                    : (u * BSZ + (cc - aCh) * 32);
        const int p  = base + key;
        const int gp = rot ? ((p + BSZ - 1) & (NT - 1)) : p;
        rK[it] = *(const float4*)(kb + (size_t)gp * DH + c0);
        rV[it] = *(const float4*)(vb + (size_t)gp * DH + c0);
      }
    }
  };
  auto WR = [&](int buf) {
#pragma unroll
    for (int it = 0; it < 2; ++it) {
      const int f   = t + 256 * it;
      const int key = f >> 4;
      const int c0  = (f & 15) * 4;
      const float kv[4] = {rK[it].x, rK[it].y, rK[it].z, rK[it].w};
      u16x4 kh4, kl4;
#pragma unroll
      for (int e = 0; e < 4; ++e) {
        const unsigned short hi = bfhi(kv[e]);
        kh4[e] = hi;
        kl4[e] = bfhi(kv[e] - bf2f(hi));
      }
      const int di = c0 ^ ((key & 7) << 3);          // 4-ushort block safe (mask mult of 8)
      *(u16x4*)&sK[buf][0][key * 64 + di] = kh4;
      *(u16x4*)&sK[buf][1][key * 64 + di] = kl4;
      const float vv[4] = {rV[it].x, rV[it].y, rV[it].z, rV[it].w};
#pragma unroll
      for (int e = 0; e < 4; ++e) {
        const int dim = c0 + e;
        const unsigned short hi = bfhi(vv[e]);
        sVT[buf][0][dim * 40 + key] = hi;
        sVT[buf][1][dim * 40 + key] = bfhi(vv[e] - bf2f(hi));
      }
    }
  };

  LD(0); WR(0);
  __syncthreads();
  int cur = 0;

  for (int cc = 0; cc < nCh; ++cc) {
    const bool last = (cc + 1 == nCh);
    if (!last) LD(cc + 1);                 // issue next-chunk global loads early

    const bool isA = (cc < aCh);
    const int  jB  = (cc - aCh) * 32;      // own-bucket chunk base (valid when !isA)
    const bool doIt = isA ? (!special || w == 0) : (jB <= w * 32 + 31);

    if (doIt) {
      // ---- K B-frags: col=key=ct*16+lc, k = kh*32 + 8*lg + i
      bfrag Kh[2][2], Kl[2][2];
#pragma unroll
      for (int ct = 0; ct < 2; ++ct) {
        const int key = ct * 16 + lc;
#pragma unroll
        for (int kh = 0; kh < 2; ++kh) {
          const int di = (kh * 32 + lg * 8) ^ ((key & 7) << 3);
          Kh[ct][kh] = *(const bfrag*)&sK[cur][0][key * 64 + di];
          Kl[ct][kh] = *(const bfrag*)&sK[cur][1][key * 64 + di];
        }
      }
      // ---- V B-frags: col=dim=dt*16+lc, k = key = 8*lg + i
      bfrag Vh[4], Vl[4];
#pragma unroll
      for (int dt = 0; dt < 4; ++dt) {
        const int dim = dt * 16 + lc;
        Vh[dt] = *(const bfrag*)&sVT[cur][0][dim * 40 + lg * 8];
        Vl[dt] = *(const bfrag*)&sVT[cur][1][dim * 40 + lg * 8];
      }

      const float lsc  = isA ? cw1 : 0.125f;
      const float lmul = (isA && s == 0) ? 4.f : 1.f;   // null multiplicity
      const float pvs  = isA ? (lmul * wq) : 1.f;       // fold reorder wgt (+mult) into P

#pragma unroll
      for (int rt = 0; rt < 2; ++rt) {
        // ---- QK^T: S = qh*kh + qh*kl + ql*kh  (both k-halves)
        ffrag S[2];
#pragma unroll
        for (int ct = 0; ct < 2; ++ct) {
          ffrag acc = ffrag{0.f, 0.f, 0.f, 0.f};
#pragma unroll
          for (int kh = 0; kh < 2; ++kh) {
            acc = __builtin_amdgcn_mfma_f32_16x16x32_bf16(qh[rt][kh], Kh[ct][kh], acc, 0, 0, 0);
            acc = __builtin_amdgcn_mfma_f32_16x16x32_bf16(qh[rt][kh], Kl[ct][kh], acc, 0, 0, 0);
            acc = __builtin_amdgcn_mfma_f32_16x16x32_bf16(ql[rt][kh], Kh[ct][kh], acc, 0, 0, 0);
          }
          S[ct] = acc;
        }
        // ---- mask + logit scale; C layout: row=(lg*4+reg)+rt*16+w*32, col=lc
        float dv[2][4]; bool vld[2][4];
#pragma unroll
        for (int ct = 0; ct < 2; ++ct)
#pragma unroll
          for (int reg = 0; reg < 4; ++reg) {
            const int row = w * 32 + rt * 16 + lg * 4 + reg;
            const int j   = jB + ct * 16 + lc;
            const bool ok = isA ? (!special || row == 0)
                                : (special ? (row == 0 ? (j == 0) : (j >= 1 && j <= row))
                                           : (j <= row));
            vld[ct][reg] = ok;
            dv[ct][reg]  = ok ? S[ct][reg] * lsc : -1e30f;
          }
        // ---- row max across 16 cols (4-step butterfly within col group)
        float pm[4];
#pragma unroll
        for (int reg = 0; reg < 4; ++reg) pm[reg] = fmaxf(dv[0][reg], dv[1][reg]);
#pragma unroll
        for (int off = 1; off <= 8; off <<= 1)
#pragma unroll
          for (int reg = 0; reg < 4; ++reg)
            pm[reg] = fmaxf(pm[reg], __shfl_xor(pm[reg], off));
        // ---- online update + P + transpose P through per-wave LDS
#pragma unroll
        for (int reg = 0; reg < 4; ++reg) {
          const float mn   = fmaxf(mR[rt][reg], pm[reg]);
          const float corr = __expf(mR[rt][reg] - mn);
          mR[rt][reg] = mn;
          lR[rt][reg] *= corr;
#pragma unroll
          for (int dt = 0; dt < 4; ++dt) O[rt][dt][reg] *= corr;
          const int row16 = lg * 4 + reg;
#pragma unroll
          for (int ct = 0; ct < 2; ++ct) {
            const float p = vld[ct][reg] ? __expf(dv[ct][reg] - mn) : 0.f;  // explicit 0 for masked
            lR[rt][reg] += lmul * p;
            const float pw = p * pvs;
            const unsigned short ph = bfhi(pw);
            sP[w][0][row16 * 40 + ct * 16 + lc] = ph;
            sP[w][1][row16 * 40 + ct * 16 + lc] = bfhi(pw - bf2f(ph));
          }
        }
        // wave-internal: ensure P writes land before frag reads
        asm volatile("s_waitcnt lgkmcnt(0)" ::: "memory");
        // ---- P A-frags: row=lc, k=keys 8*lg+i
        const bfrag Ph = *(const bfrag*)&sP[w][0][lc * 40 + lg * 8];
        const bfrag Pl = *(const bfrag*)&sP[w][1][lc * 40 + lg * 8];
        // ---- PV: O += Ph*Vh + Ph*Vl + Pl*Vh
#pragma unroll
        for (int dt = 0; dt < 4; ++dt) {
          ffrag acc = O[rt][dt];
          acc = __builtin_amdgcn_mfma_f32_16x16x32_bf16(Ph, Vh[dt], acc, 0, 0, 0);
          acc = __builtin_amdgcn_mfma_f32_16x16x32_bf16(Ph, Vl[dt], acc, 0, 0, 0);
          acc = __builtin_amdgcn_mfma_f32_16x16x32_bf16(Pl, Vh[dt], acc, 0, 0, 0);
          O[rt][dt] = acc;
        }
      }
    }

    if (!last) WR(cur ^ 1);                // write next chunk after compute (T14)
    __syncthreads();
    cur ^= 1;
  }

  // ---- finalize: reduce l across the 16-lane col group, normalize, store
#pragma unroll
  for (int rt = 0; rt < 2; ++rt) {
#pragma unroll
    for (int off = 1; off <= 8; off <<= 1)
#pragma unroll
      for (int reg = 0; reg < 4; ++reg)
        lR[rt][reg] += __shfl_xor(lR[rt][reg], off);
#pragma unroll
    for (int reg = 0; reg < 4; ++reg) {
      const float rl = 1.0f / lR[rt][reg];
      const int row  = w * 32 + rt * 16 + lg * 4 + reg;
      const int pos  = u * BSZ + row;
      const int gpos = rot ? ((pos + BSZ - 1) & (NT - 1)) : pos;
      float* op = out + (size_t)(((size_t)bh * NT + gpos) * DH);
#pragma unroll
      for (int dt = 0; dt < 4; ++dt)
        op[dt * 16 + lc] = O[rt][dt][reg] * rl;
    }
  }
}

// -------------------------------------------------------------------------
extern "C" void kernel_launch(void* const* d_in, const int* in_sizes, int n_in,
                              void* d_out, int out_size, void* d_ws, size_t ws_size,
                              hipStream_t stream) {
  const float* q  = (const float*)d_in[0];
  const float* k  = (const float*)d_in[1];
  const float* v  = (const float*)d_in[2];
  const float* nk = (const float*)d_in[3];
  const float* nv = (const float*)d_in[4];
  float* out = (float*)d_out;

  float* wsf  = (float*)d_ws;
  float* wgt  = wsf;                              // BH*NBK floats
  int*   srcb = (int*)(wsf + BH * NBK);           // BH*NBK ints
  float* Bq   = wsf + 2 * BH * NBK;
  float* Bk   = Bq + (size_t)BH * NBK * DH;
  float* q0   = Bk + (size_t)BH * NBK * DH;
  float* skp  = q0 + (size_t)BH * NBK * DH;

  hipLaunchKernelGGL(k_stats, dim3(BH * NBK), dim3(256), 0, stream,
                     q, k, Bq, Bk, q0, skp);
  hipLaunchKernelGGL(k_sortnet, dim3(BH), dim3(256), 0, stream,
                     Bq, Bk, q0, skp, wgt, srcb);
  hipLaunchKernelGGL(k_attn, dim3(BH * NBK), dim3(256), 0, stream,
                     q, k, v, nk, nv, wgt, srcb, out);
}